// Round 11
// baseline (321.677 us; speedup 1.0000x reference)
//
#include <hip/hip_runtime.h>

// 3-layer GCN + mean pool. bf16 storage / MFMA GEMM / fp32 accumulate.
// R11: weightless edges via row pre-scaling.
//   h' = h * dinv stored per row (scaled in the previous layer's epilogue /
//   xcast), so agg[d] = dinv[d] * (sum_src h'[src] + h'[d]) needs NO
//   per-edge weight: col is 4 B/edge, scatter does no dinv gathers.
//   Layer-3 epilogue unscaled (pool needs raw h3).
// Fused layer kernels otherwise as R10 (at the ~2.5 TB/s random-gather wall).

#define DIN 30
#define HD  128

typedef __attribute__((ext_vector_type(8))) short v8s;
typedef __attribute__((ext_vector_type(4))) float v4f;

static __device__ __forceinline__ unsigned short f2bf(float f) {
  unsigned int u = __float_as_uint(f);
  u += 0x7fffu + ((u >> 16) & 1u);   // RNE
  return (unsigned short)(u >> 16);
}
static __device__ __forceinline__ float bf2f(unsigned short s) {
  return __uint_as_float(((unsigned int)s) << 16);
}
static __device__ __forceinline__ float bflo(unsigned int u) {
  return __uint_as_float(u << 16);
}
static __device__ __forceinline__ float bfhi(unsigned int u) {
  return __uint_as_float(u & 0xffff0000u);
}

// ---------------- preprocessing ----------------
__global__ void k_degree(const int* __restrict__ dst, int* __restrict__ deg, int E) {
  int e = blockIdx.x * blockDim.x + threadIdx.x;
  if (e < E) atomicAdd(&deg[dst[e]], 1);
}

__global__ void k_scan1(const int* __restrict__ deg, int* __restrict__ bsum, int N) {
  __shared__ int s[256];
  int tid = threadIdx.x;
  int base = blockIdx.x * 1024 + tid * 4;
  int t = 0;
#pragma unroll
  for (int j = 0; j < 4; ++j) { int idx = base + j; if (idx < N) t += deg[idx]; }
  s[tid] = t; __syncthreads();
  for (int d = 128; d > 0; d >>= 1) { if (tid < d) s[tid] += s[tid + d]; __syncthreads(); }
  if (tid == 0) bsum[blockIdx.x] = s[0];
}

__global__ void k_scan2(const int* __restrict__ bsum, int* __restrict__ boff, int nb) {
  __shared__ int s[256];
  int tid = threadIdx.x;
  int v = (tid < nb) ? bsum[tid] : 0;
  s[tid] = v; __syncthreads();
  for (int d = 1; d < 256; d <<= 1) {
    int t = (tid >= d) ? s[tid - d] : 0;
    __syncthreads();
    s[tid] += t;
    __syncthreads();
  }
  boff[tid] = s[tid] - v;
}

// scan3 + dinv fused
__global__ void k_scan3(const int* __restrict__ deg, const int* __restrict__ boff,
                        int* __restrict__ rowptr, int* __restrict__ cursor,
                        float* __restrict__ dinv, int N) {
  __shared__ int s[256];
  int tid = threadIdx.x;
  int base = blockIdx.x * 1024 + tid * 4;
  int v[4]; int t = 0;
#pragma unroll
  for (int j = 0; j < 4; ++j) { int idx = base + j; v[j] = (idx < N) ? deg[idx] : 0; t += v[j]; }
  s[tid] = t; __syncthreads();
  for (int d = 1; d < 256; d <<= 1) {
    int u = (tid >= d) ? s[tid - d] : 0;
    __syncthreads();
    s[tid] += u;
    __syncthreads();
  }
  int run = boff[blockIdx.x] + s[tid] - t;
#pragma unroll
  for (int j = 0; j < 4; ++j) {
    int idx = base + j;
    if (idx < N) {
      rowptr[idx] = run; cursor[idx] = run;
      dinv[idx] = rsqrtf((float)(1 + v[j]));
    }
    run += v[j];
    if (idx == N - 1) rowptr[N] = run;
  }
}

// fragment-major weight pack helper
static __device__ __forceinline__ void wtf_one(const float* __restrict__ W,
                                               unsigned short* __restrict__ WTF,
                                               int idx, int Kreal, int KK) {
  int j = idx & 7;
  int c = idx >> 3;
  int l15 = c & 15;
  int quad = (c >> 4) & 3;
  int kk = (c >> 6) % KK;
  int t = c / (64 * KK);
  int k = kk * 32 + quad * 8 + j;
  int n = t * 16 + l15;
  WTF[idx] = (k < Kreal) ? f2bf(W[k * 128 + n]) : (unsigned short)0;
}

// merged post-scan prep: CSR col scatter | xcast (x*dinv -> bf16) | wtf | bounds
__global__ void k_prep(const int* __restrict__ src, const int* __restrict__ dst,
                       int* __restrict__ cursor, int* __restrict__ col, int E,
                       const float* __restrict__ x, const float* __restrict__ dinv,
                       unsigned short* __restrict__ xb, int N,
                       const float* __restrict__ W1, const float* __restrict__ W2,
                       const float* __restrict__ W3,
                       unsigned short* __restrict__ W1F, unsigned short* __restrict__ W2F,
                       unsigned short* __restrict__ W3F,
                       const int* __restrict__ batch, int* __restrict__ gstart, int G,
                       int SB, int XB, int WB) {
  int blk = blockIdx.x;
  if (blk < SB) {
    int e = blk * 256 + threadIdx.x;
    if (e < E) {
      int d = dst[e];
      int pos = atomicAdd(&cursor[d], 1);
      col[pos] = src[e];
    }
  } else if (blk < SB + XB) {
    int idx = (blk - SB) * 256 + threadIdx.x;
    if (idx < N * 32) {
      int n = idx >> 5, f = idx & 31;
      float v = (f < DIN) ? x[(size_t)n * DIN + f] * dinv[n] : 0.f;
      xb[idx] = f2bf(v);
    }
  } else if (blk < SB + XB + WB) {
    int idx = (blk - SB - XB) * 256 + threadIdx.x;
    if (idx < 4096) wtf_one(W1, W1F, idx, DIN, 1);
    else if (idx < 20480) wtf_one(W2, W2F, idx - 4096, 128, 4);
    else if (idx < 36864) wtf_one(W3, W3F, idx - 20480, 128, 4);
  } else {
    int i = (blk - SB - XB - WB) * 256 + threadIdx.x;
    if (i >= N) return;
    int b = batch[i];
    int prev = (i == 0) ? -1 : batch[i - 1];
    for (int g = prev + 1; g <= b; ++g) gstart[g] = i;
    if (i == N - 1)
      for (int g = b + 1; g <= G; ++g) gstart[g] = N;
  }
}

// ---------------- fused aggregate + MFMA GEMM (layers 1,2) ----------------
// Phase 1: agg = dinv[node] * (sum h'[col] + h'[node]); phase 2 MFMA;
// epilogue: store relu(.)*dinv[row] (pre-scaled for the next layer).
template <int K>
__global__ __launch_bounds__(1024, 8) void k_fused(const unsigned short* __restrict__ hin,
                                                   const unsigned short* __restrict__ WTF,
                                                   const float* __restrict__ b,
                                                   const int* __restrict__ rowptr,
                                                   const int* __restrict__ col,
                                                   const float* __restrict__ dinv,
                                                   unsigned short* __restrict__ C, int N) {
  constexpr int KK = K / 32;
  constexpr int KP = (K == 128) ? 136 : 40;
  constexpr int CP = 132;
  constexpr int SMSZ = (64 * KP > 64 * CP) ? 64 * KP : 64 * CP;
  __shared__ __align__(16) unsigned short sm[SMSZ];

  int tid = threadIdx.x;
  int l16 = tid & 15;
  int nl = tid >> 4;
  int row0 = blockIdx.x * 64;
  int node = row0 + nl;

  // ---- phase 1 ----
  if (K == 32) {
    const unsigned int* hp = (const unsigned int*)hin;
    float a0 = 0.f, a1 = 0.f;
    if (node < N) {
      unsigned int u = hp[(size_t)node * 16 + l16];
      a0 = bflo(u); a1 = bfhi(u);
      int e0 = rowptr[node], e1 = rowptr[node + 1];
      int e = e0;
      for (; e + 2 <= e1; e += 2) {
        int c0 = col[e], c1 = col[e + 1];
        unsigned int v0 = hp[(size_t)c0 * 16 + l16];
        unsigned int v1 = hp[(size_t)c1 * 16 + l16];
        a0 += bflo(v0); a1 += bfhi(v0);
        a0 += bflo(v1); a1 += bfhi(v1);
      }
      if (e < e1) {
        unsigned int v0 = hp[(size_t)col[e] * 16 + l16];
        a0 += bflo(v0); a1 += bfhi(v0);
      }
      float di = dinv[node];
      a0 *= di; a1 *= di;
    }
    *(unsigned int*)&sm[nl * KP + l16 * 2] =
        (unsigned int)f2bf(a0) | ((unsigned int)f2bf(a1) << 16);
  } else {
    const uint4* hp = (const uint4*)hin;
    float a0 = 0.f, a1 = 0.f, a2 = 0.f, a3 = 0.f, a4 = 0.f, a5 = 0.f, a6 = 0.f, a7 = 0.f;
    if (node < N) {
      uint4 u = hp[(size_t)node * 16 + l16];
      a0 = bflo(u.x); a1 = bfhi(u.x);
      a2 = bflo(u.y); a3 = bfhi(u.y);
      a4 = bflo(u.z); a5 = bfhi(u.z);
      a6 = bflo(u.w); a7 = bfhi(u.w);
      int e0 = rowptr[node], e1 = rowptr[node + 1];
      int e = e0;
      for (; e + 2 <= e1; e += 2) {
        int c0 = col[e], c1 = col[e + 1];
        uint4 v0 = hp[(size_t)c0 * 16 + l16];
        uint4 v1 = hp[(size_t)c1 * 16 + l16];
        a0 += bflo(v0.x); a1 += bfhi(v0.x);
        a2 += bflo(v0.y); a3 += bfhi(v0.y);
        a4 += bflo(v0.z); a5 += bfhi(v0.z);
        a6 += bflo(v0.w); a7 += bfhi(v0.w);
        a0 += bflo(v1.x); a1 += bfhi(v1.x);
        a2 += bflo(v1.y); a3 += bfhi(v1.y);
        a4 += bflo(v1.z); a5 += bfhi(v1.z);
        a6 += bflo(v1.w); a7 += bfhi(v1.w);
      }
      if (e < e1) {
        uint4 v0 = hp[(size_t)col[e] * 16 + l16];
        a0 += bflo(v0.x); a1 += bfhi(v0.x);
        a2 += bflo(v0.y); a3 += bfhi(v0.y);
        a4 += bflo(v0.z); a5 += bfhi(v0.z);
        a6 += bflo(v0.w); a7 += bfhi(v0.w);
      }
      float di = dinv[node];
      a0 *= di; a1 *= di; a2 *= di; a3 *= di;
      a4 *= di; a5 *= di; a6 *= di; a7 *= di;
    }
    uint4 o;
    o.x = (unsigned int)f2bf(a0) | ((unsigned int)f2bf(a1) << 16);
    o.y = (unsigned int)f2bf(a2) | ((unsigned int)f2bf(a3) << 16);
    o.z = (unsigned int)f2bf(a4) | ((unsigned int)f2bf(a5) << 16);
    o.w = (unsigned int)f2bf(a6) | ((unsigned int)f2bf(a7) << 16);
    *(uint4*)&sm[nl * KP + l16 * 8] = o;
  }
  __syncthreads();

  // ---- phase 2: A-frags from LDS; 16 waves = 4 row-tiles x 4 t-pairs ----
  int wv = tid >> 6, lane = tid & 63, quad = lane >> 4, l15 = lane & 15;
  int rt = wv & 3, tp = wv >> 2;
  v8s af[KK];
#pragma unroll
  for (int kk = 0; kk < KK; ++kk)
    af[kk] = *(const v8s*)&sm[(rt * 16 + l15) * KP + kk * 32 + quad * 8];
  __syncthreads();

#pragma unroll
  for (int tt = 0; tt < 2; ++tt) {
    int t = tp * 2 + tt;
    v4f acc = {0.f, 0.f, 0.f, 0.f};
#pragma unroll
    for (int kk = 0; kk < KK; ++kk) {
      v8s bf = *(const v8s*)(WTF + (size_t)(((t * KK + kk) * 4 + quad) * 16 + l15) * 8);
      acc = __builtin_amdgcn_mfma_f32_16x16x32_bf16(af[kk], bf, acc, 0, 0, 0);
    }
    float bias = b[t * 16 + l15];
#pragma unroll
    for (int i = 0; i < 4; ++i) {
      int crow = row0 + rt * 16 + quad * 4 + i;
      float dr = (crow < N) ? dinv[crow] : 0.f;     // pre-scale for next layer
      float o = fmaxf(acc[i] + bias, 0.f) * dr;
      sm[(rt * 16 + quad * 4 + i) * CP + t * 16 + l15] = f2bf(o);
    }
  }
  __syncthreads();

  // ---- phase 3: coalesced C store ----
#pragma unroll
  for (int j = 0; j < 2; ++j) {
    int linear = j * 1024 + tid;
    int r = linear >> 5, ch = linear & 31;
    uint2 v = *(const uint2*)&sm[r * CP + ch * 4];
    int row = row0 + r;
    if (row < N) ((uint2*)C)[(size_t)row * 32 + ch] = v;
  }
}

// ---------------- layer 3: fused aggregate + GEMM + pool-atomics ----------------
__global__ __launch_bounds__(1024, 8) void k_fused_pool(const unsigned short* __restrict__ hin,
                                                        const unsigned short* __restrict__ WTF,
                                                        const float* __restrict__ b,
                                                        const int* __restrict__ rowptr,
                                                        const int* __restrict__ col,
                                                        const float* __restrict__ dinv,
                                                        const int* __restrict__ batch,
                                                        float* __restrict__ out, int N) {
  constexpr int KK = 4, KP = 136, CP = 132;
  constexpr int SMSZ = 64 * KP;
  __shared__ __align__(16) unsigned short sm[SMSZ];
  __shared__ int sbatch[64];

  int tid = threadIdx.x;
  int l16 = tid & 15;
  int nl = tid >> 4;
  int row0 = blockIdx.x * 64;
  int node = row0 + nl;

  if (tid < 64) sbatch[tid] = (row0 + tid < N) ? batch[row0 + tid] : -1;

  // ---- phase 1 ----
  {
    const uint4* hp = (const uint4*)hin;
    float a0 = 0.f, a1 = 0.f, a2 = 0.f, a3 = 0.f, a4 = 0.f, a5 = 0.f, a6 = 0.f, a7 = 0.f;
    if (node < N) {
      uint4 u = hp[(size_t)node * 16 + l16];
      a0 = bflo(u.x); a1 = bfhi(u.x);
      a2 = bflo(u.y); a3 = bfhi(u.y);
      a4 = bflo(u.z); a5 = bfhi(u.z);
      a6 = bflo(u.w); a7 = bfhi(u.w);
      int e0 = rowptr[node], e1 = rowptr[node + 1];
      int e = e0;
      for (; e + 2 <= e1; e += 2) {
        int c0 = col[e], c1 = col[e + 1];
        uint4 v0 = hp[(size_t)c0 * 16 + l16];
        uint4 v1 = hp[(size_t)c1 * 16 + l16];
        a0 += bflo(v0.x); a1 += bfhi(v0.x);
        a2 += bflo(v0.y); a3 += bfhi(v0.y);
        a4 += bflo(v0.z); a5 += bfhi(v0.z);
        a6 += bflo(v0.w); a7 += bfhi(v0.w);
        a0 += bflo(v1.x); a1 += bfhi(v1.x);
        a2 += bflo(v1.y); a3 += bfhi(v1.y);
        a4 += bflo(v1.z); a5 += bfhi(v1.z);
        a6 += bflo(v1.w); a7 += bfhi(v1.w);
      }
      if (e < e1) {
        uint4 v0 = hp[(size_t)col[e] * 16 + l16];
        a0 += bflo(v0.x); a1 += bfhi(v0.x);
        a2 += bflo(v0.y); a3 += bfhi(v0.y);
        a4 += bflo(v0.z); a5 += bfhi(v0.z);
        a6 += bflo(v0.w); a7 += bfhi(v0.w);
      }
      float di = dinv[node];
      a0 *= di; a1 *= di; a2 *= di; a3 *= di;
      a4 *= di; a5 *= di; a6 *= di; a7 *= di;
    }
    uint4 o;
    o.x = (unsigned int)f2bf(a0) | ((unsigned int)f2bf(a1) << 16);
    o.y = (unsigned int)f2bf(a2) | ((unsigned int)f2bf(a3) << 16);
    o.z = (unsigned int)f2bf(a4) | ((unsigned int)f2bf(a5) << 16);
    o.w = (unsigned int)f2bf(a6) | ((unsigned int)f2bf(a7) << 16);
    *(uint4*)&sm[nl * KP + l16 * 8] = o;
  }
  __syncthreads();

  // ---- phase 2 (no epilogue scaling: pool needs raw h3) ----
  int wv = tid >> 6, lane = tid & 63, quad = lane >> 4, l15 = lane & 15;
  int rt = wv & 3, tp = wv >> 2;
  v8s af[KK];
#pragma unroll
  for (int kk = 0; kk < KK; ++kk)
    af[kk] = *(const v8s*)&sm[(rt * 16 + l15) * KP + kk * 32 + quad * 8];
  __syncthreads();

#pragma unroll
  for (int tt = 0; tt < 2; ++tt) {
    int t = tp * 2 + tt;
    v4f acc = {0.f, 0.f, 0.f, 0.f};
#pragma unroll
    for (int kk = 0; kk < KK; ++kk) {
      v8s bf = *(const v8s*)(WTF + (size_t)(((t * KK + kk) * 4 + quad) * 16 + l15) * 8);
      acc = __builtin_amdgcn_mfma_f32_16x16x32_bf16(af[kk], bf, acc, 0, 0, 0);
    }
    float bias = b[t * 16 + l15];
#pragma unroll
    for (int i = 0; i < 4; ++i) {
      float o = fmaxf(acc[i] + bias, 0.f);
      sm[(rt * 16 + quad * 4 + i) * CP + t * 16 + l15] = f2bf(o);
    }
  }
  __syncthreads();

  // ---- phase 3: segment-sum the 64 sorted rows, atomicAdd partials ----
  int f = tid & 127;
  int grp = tid >> 7;
  float run = 0.f;
  int cur = -1;
#pragma unroll
  for (int j = 0; j < 8; ++j) {
    int r = grp * 8 + j;
    int g = sbatch[r];
    if (g != cur) {
      if (cur >= 0) atomicAdd(&out[(size_t)cur * 128 + f], run);
      run = 0.f; cur = g;
    }
    if (g >= 0) run += bf2f(sm[r * CP + f]);
  }
  if (cur >= 0) atomicAdd(&out[(size_t)cur * 128 + f], run);
}

// divide pooled sums by segment counts
__global__ void k_finalize(float* __restrict__ out, const int* __restrict__ gstart, int G) {
  int idx = blockIdx.x * blockDim.x + threadIdx.x;
  if (idx >= G * 128) return;
  int g = idx >> 7;
  float cnt = (float)(gstart[g + 1] - gstart[g]);
  out[idx] = out[idx] / fmaxf(cnt, 1.f);
}

extern "C" void kernel_launch(void* const* d_in, const int* in_sizes, int n_in,
                              void* d_out, int out_size, void* d_ws, size_t ws_size,
                              hipStream_t stream) {
  const float* x  = (const float*)d_in[0];
  const int* ei   = (const int*)d_in[1];
  const int* batch = (const int*)d_in[2];
  const float* W1 = (const float*)d_in[3];
  const float* b1 = (const float*)d_in[4];
  const float* W2 = (const float*)d_in[5];
  const float* b2 = (const float*)d_in[6];
  const float* W3 = (const float*)d_in[7];
  const float* b3 = (const float*)d_in[8];
  float* out = (float*)d_out;
  int N = in_sizes[2];
  int E = in_sizes[1] / 2;
  int G = out_size / HD;
  const int* src = ei;
  const int* dst = ei + E;

  size_t off = 0;
  char* ws = (char*)d_ws;
  auto alloc = [&](size_t bytes) -> void* {
    void* p = ws + off;
    off += (bytes + 255) & ~(size_t)255;
    return p;
  };
  int*   deg    = (int*)alloc((size_t)N * 4);
  float* dinv   = (float*)alloc((size_t)N * 4);
  int*   rowptr = (int*)alloc((size_t)(N + 1) * 4);
  int*   cursor = (int*)alloc((size_t)N * 4);
  int*   col    = (int*)alloc((size_t)E * 4);
  int*   bsum   = (int*)alloc(256 * 4);
  int*   boff   = (int*)alloc(256 * 4);
  int*   gstart = (int*)alloc((size_t)(G + 1) * 4);
  unsigned short* xb  = (unsigned short*)alloc((size_t)N * 32 * 2);
  unsigned short* hA  = (unsigned short*)alloc((size_t)N * HD * 2);
  unsigned short* hB  = (unsigned short*)alloc((size_t)N * HD * 2);
  unsigned short* W1F = (unsigned short*)alloc(4096 * 2);
  unsigned short* W2F = (unsigned short*)alloc(16384 * 2);
  unsigned short* W3F = (unsigned short*)alloc(16384 * 2);
  (void)ws_size; (void)n_in;

  int nb1024 = (N + 1023) / 1024;
  hipMemsetAsync(deg, 0, (size_t)N * 4, stream);
  hipMemsetAsync(out, 0, (size_t)out_size * 4, stream);
  k_degree<<<(E + 255) / 256, 256, 0, stream>>>(dst, deg, E);
  k_scan1<<<nb1024, 256, 0, stream>>>(deg, bsum, N);
  k_scan2<<<1, 256, 0, stream>>>(bsum, boff, nb1024);
  k_scan3<<<nb1024, 256, 0, stream>>>(deg, boff, rowptr, cursor, dinv, N);

  int SB = (E + 255) / 256;
  int XB = (N * 32 + 255) / 256;
  int WB = 144;
  int BB = (N + 255) / 256;
  k_prep<<<SB + XB + WB + BB, 256, 0, stream>>>(src, dst, cursor, col, E,
                                                x, dinv, xb, N,
                                                W1, W2, W3, W1F, W2F, W3F,
                                                batch, gstart, G, SB, XB, WB);

  int fusedBlocks = (N + 63) / 64;
  k_fused<32><<<fusedBlocks, 1024, 0, stream>>>(xb, W1F, b1, rowptr, col, dinv, hA, N);
  k_fused<128><<<fusedBlocks, 1024, 0, stream>>>(hA, W2F, b2, rowptr, col, dinv, hB, N);
  k_fused_pool<<<fusedBlocks, 1024, 0, stream>>>(hB, W3F, b3, rowptr, col, dinv, batch, out, N);
  k_finalize<<<(G * 128 + 255) / 256, 256, 0, stream>>>(out, gstart, G);
}

// Round 12
// 315.947 us; speedup vs baseline: 1.0181x; 1.0181x over previous
//
#include <hip/hip_runtime.h>

// 3-layer GCN + mean pool. bf16 storage / MFMA GEMM / fp32 accumulate.
// R12: R11 (weightless edges via row pre-scaling) with the epilogue fixed:
//   - dinv epilogue scale hoisted to one float4 load before the MFMA t-loop
//   - nontemporal C stores (h never re-read by producer; save L2 for gathers)
// Fused gather kernels are at the measured ~2.4-2.5 TB/s random-gather wall
// (R9: occupancy 40%->72% left duration unchanged).

#define DIN 30
#define HD  128

typedef __attribute__((ext_vector_type(8))) short v8s;
typedef __attribute__((ext_vector_type(4))) float v4f;

static __device__ __forceinline__ unsigned short f2bf(float f) {
  unsigned int u = __float_as_uint(f);
  u += 0x7fffu + ((u >> 16) & 1u);   // RNE
  return (unsigned short)(u >> 16);
}
static __device__ __forceinline__ float bf2f(unsigned short s) {
  return __uint_as_float(((unsigned int)s) << 16);
}
static __device__ __forceinline__ float bflo(unsigned int u) {
  return __uint_as_float(u << 16);
}
static __device__ __forceinline__ float bfhi(unsigned int u) {
  return __uint_as_float(u & 0xffff0000u);
}

// ---------------- preprocessing ----------------
__global__ void k_degree(const int* __restrict__ dst, int* __restrict__ deg, int E) {
  int e = blockIdx.x * blockDim.x + threadIdx.x;
  if (e < E) atomicAdd(&deg[dst[e]], 1);
}

__global__ void k_scan1(const int* __restrict__ deg, int* __restrict__ bsum, int N) {
  __shared__ int s[256];
  int tid = threadIdx.x;
  int base = blockIdx.x * 1024 + tid * 4;
  int t = 0;
#pragma unroll
  for (int j = 0; j < 4; ++j) { int idx = base + j; if (idx < N) t += deg[idx]; }
  s[tid] = t; __syncthreads();
  for (int d = 128; d > 0; d >>= 1) { if (tid < d) s[tid] += s[tid + d]; __syncthreads(); }
  if (tid == 0) bsum[blockIdx.x] = s[0];
}

__global__ void k_scan2(const int* __restrict__ bsum, int* __restrict__ boff, int nb) {
  __shared__ int s[256];
  int tid = threadIdx.x;
  int v = (tid < nb) ? bsum[tid] : 0;
  s[tid] = v; __syncthreads();
  for (int d = 1; d < 256; d <<= 1) {
    int t = (tid >= d) ? s[tid - d] : 0;
    __syncthreads();
    s[tid] += t;
    __syncthreads();
  }
  boff[tid] = s[tid] - v;
}

// scan3 + dinv fused
__global__ void k_scan3(const int* __restrict__ deg, const int* __restrict__ boff,
                        int* __restrict__ rowptr, int* __restrict__ cursor,
                        float* __restrict__ dinv, int N) {
  __shared__ int s[256];
  int tid = threadIdx.x;
  int base = blockIdx.x * 1024 + tid * 4;
  int v[4]; int t = 0;
#pragma unroll
  for (int j = 0; j < 4; ++j) { int idx = base + j; v[j] = (idx < N) ? deg[idx] : 0; t += v[j]; }
  s[tid] = t; __syncthreads();
  for (int d = 1; d < 256; d <<= 1) {
    int u = (tid >= d) ? s[tid - d] : 0;
    __syncthreads();
    s[tid] += u;
    __syncthreads();
  }
  int run = boff[blockIdx.x] + s[tid] - t;
#pragma unroll
  for (int j = 0; j < 4; ++j) {
    int idx = base + j;
    if (idx < N) {
      rowptr[idx] = run; cursor[idx] = run;
      dinv[idx] = rsqrtf((float)(1 + v[j]));
    }
    run += v[j];
    if (idx == N - 1) rowptr[N] = run;
  }
}

// fragment-major weight pack helper
static __device__ __forceinline__ void wtf_one(const float* __restrict__ W,
                                               unsigned short* __restrict__ WTF,
                                               int idx, int Kreal, int KK) {
  int j = idx & 7;
  int c = idx >> 3;
  int l15 = c & 15;
  int quad = (c >> 4) & 3;
  int kk = (c >> 6) % KK;
  int t = c / (64 * KK);
  int k = kk * 32 + quad * 8 + j;
  int n = t * 16 + l15;
  WTF[idx] = (k < Kreal) ? f2bf(W[k * 128 + n]) : (unsigned short)0;
}

// merged post-scan prep: CSR col scatter | xcast (x*dinv -> bf16) | wtf | bounds
__global__ void k_prep(const int* __restrict__ src, const int* __restrict__ dst,
                       int* __restrict__ cursor, int* __restrict__ col, int E,
                       const float* __restrict__ x, const float* __restrict__ dinv,
                       unsigned short* __restrict__ xb, int N,
                       const float* __restrict__ W1, const float* __restrict__ W2,
                       const float* __restrict__ W3,
                       unsigned short* __restrict__ W1F, unsigned short* __restrict__ W2F,
                       unsigned short* __restrict__ W3F,
                       const int* __restrict__ batch, int* __restrict__ gstart, int G,
                       int SB, int XB, int WB) {
  int blk = blockIdx.x;
  if (blk < SB) {
    int e = blk * 256 + threadIdx.x;
    if (e < E) {
      int d = dst[e];
      int pos = atomicAdd(&cursor[d], 1);
      col[pos] = src[e];
    }
  } else if (blk < SB + XB) {
    int idx = (blk - SB) * 256 + threadIdx.x;
    if (idx < N * 32) {
      int n = idx >> 5, f = idx & 31;
      float v = (f < DIN) ? x[(size_t)n * DIN + f] * dinv[n] : 0.f;
      xb[idx] = f2bf(v);
    }
  } else if (blk < SB + XB + WB) {
    int idx = (blk - SB - XB) * 256 + threadIdx.x;
    if (idx < 4096) wtf_one(W1, W1F, idx, DIN, 1);
    else if (idx < 20480) wtf_one(W2, W2F, idx - 4096, 128, 4);
    else if (idx < 36864) wtf_one(W3, W3F, idx - 20480, 128, 4);
  } else {
    int i = (blk - SB - XB - WB) * 256 + threadIdx.x;
    if (i >= N) return;
    int b = batch[i];
    int prev = (i == 0) ? -1 : batch[i - 1];
    for (int g = prev + 1; g <= b; ++g) gstart[g] = i;
    if (i == N - 1)
      for (int g = b + 1; g <= G; ++g) gstart[g] = N;
  }
}

// ---------------- fused aggregate + MFMA GEMM (layers 1,2) ----------------
template <int K>
__global__ __launch_bounds__(1024, 8) void k_fused(const unsigned short* __restrict__ hin,
                                                   const unsigned short* __restrict__ WTF,
                                                   const float* __restrict__ b,
                                                   const int* __restrict__ rowptr,
                                                   const int* __restrict__ col,
                                                   const float* __restrict__ dinv,
                                                   unsigned short* __restrict__ C, int N) {
  constexpr int KK = K / 32;
  constexpr int KP = (K == 128) ? 136 : 40;
  constexpr int CP = 132;
  constexpr int SMSZ = (64 * KP > 64 * CP) ? 64 * KP : 64 * CP;
  __shared__ __align__(16) unsigned short sm[SMSZ];

  int tid = threadIdx.x;
  int l16 = tid & 15;
  int nl = tid >> 4;
  int row0 = blockIdx.x * 64;
  int node = row0 + nl;

  // ---- phase 1: agg = dinv[node] * (sum h'[col] + h'[node]) into LDS ----
  if (K == 32) {
    const unsigned int* hp = (const unsigned int*)hin;
    float a0 = 0.f, a1 = 0.f;
    if (node < N) {
      unsigned int u = hp[(size_t)node * 16 + l16];
      a0 = bflo(u); a1 = bfhi(u);
      int e0 = rowptr[node], e1 = rowptr[node + 1];
      int e = e0;
      for (; e + 2 <= e1; e += 2) {
        int c0 = col[e], c1 = col[e + 1];
        unsigned int v0 = hp[(size_t)c0 * 16 + l16];
        unsigned int v1 = hp[(size_t)c1 * 16 + l16];
        a0 += bflo(v0); a1 += bfhi(v0);
        a0 += bflo(v1); a1 += bfhi(v1);
      }
      if (e < e1) {
        unsigned int v0 = hp[(size_t)col[e] * 16 + l16];
        a0 += bflo(v0); a1 += bfhi(v0);
      }
      float di = dinv[node];
      a0 *= di; a1 *= di;
    }
    *(unsigned int*)&sm[nl * KP + l16 * 2] =
        (unsigned int)f2bf(a0) | ((unsigned int)f2bf(a1) << 16);
  } else {
    const uint4* hp = (const uint4*)hin;
    float a0 = 0.f, a1 = 0.f, a2 = 0.f, a3 = 0.f, a4 = 0.f, a5 = 0.f, a6 = 0.f, a7 = 0.f;
    if (node < N) {
      uint4 u = hp[(size_t)node * 16 + l16];
      a0 = bflo(u.x); a1 = bfhi(u.x);
      a2 = bflo(u.y); a3 = bfhi(u.y);
      a4 = bflo(u.z); a5 = bfhi(u.z);
      a6 = bflo(u.w); a7 = bfhi(u.w);
      int e0 = rowptr[node], e1 = rowptr[node + 1];
      int e = e0;
      for (; e + 2 <= e1; e += 2) {
        int c0 = col[e], c1 = col[e + 1];
        uint4 v0 = hp[(size_t)c0 * 16 + l16];
        uint4 v1 = hp[(size_t)c1 * 16 + l16];
        a0 += bflo(v0.x); a1 += bfhi(v0.x);
        a2 += bflo(v0.y); a3 += bfhi(v0.y);
        a4 += bflo(v0.z); a5 += bfhi(v0.z);
        a6 += bflo(v0.w); a7 += bfhi(v0.w);
        a0 += bflo(v1.x); a1 += bfhi(v1.x);
        a2 += bflo(v1.y); a3 += bfhi(v1.y);
        a4 += bflo(v1.z); a5 += bfhi(v1.z);
        a6 += bflo(v1.w); a7 += bfhi(v1.w);
      }
      if (e < e1) {
        uint4 v0 = hp[(size_t)col[e] * 16 + l16];
        a0 += bflo(v0.x); a1 += bfhi(v0.x);
        a2 += bflo(v0.y); a3 += bfhi(v0.y);
        a4 += bflo(v0.z); a5 += bfhi(v0.z);
        a6 += bflo(v0.w); a7 += bfhi(v0.w);
      }
      float di = dinv[node];
      a0 *= di; a1 *= di; a2 *= di; a3 *= di;
      a4 *= di; a5 *= di; a6 *= di; a7 *= di;
    }
    uint4 o;
    o.x = (unsigned int)f2bf(a0) | ((unsigned int)f2bf(a1) << 16);
    o.y = (unsigned int)f2bf(a2) | ((unsigned int)f2bf(a3) << 16);
    o.z = (unsigned int)f2bf(a4) | ((unsigned int)f2bf(a5) << 16);
    o.w = (unsigned int)f2bf(a6) | ((unsigned int)f2bf(a7) << 16);
    *(uint4*)&sm[nl * KP + l16 * 8] = o;
  }
  __syncthreads();

  // ---- phase 2: A-frags from LDS; 16 waves = 4 row-tiles x 4 t-pairs ----
  int wv = tid >> 6, lane = tid & 63, quad = lane >> 4, l15 = lane & 15;
  int rt = wv & 3, tp = wv >> 2;
  v8s af[KK];
#pragma unroll
  for (int kk = 0; kk < KK; ++kk)
    af[kk] = *(const v8s*)&sm[(rt * 16 + l15) * KP + kk * 32 + quad * 8];
  __syncthreads();

  // hoisted next-layer pre-scale: dinv for this lane's 4 output rows
  int crow0 = row0 + rt * 16 + quad * 4;
  float dr[4];
  if (crow0 + 3 < N) {
    float4 d4 = *(const float4*)&dinv[crow0];   // 16B-aligned (crow0 % 4 == 0)
    dr[0] = d4.x; dr[1] = d4.y; dr[2] = d4.z; dr[3] = d4.w;
  } else {
#pragma unroll
    for (int i = 0; i < 4; ++i) dr[i] = (crow0 + i < N) ? dinv[crow0 + i] : 0.f;
  }

#pragma unroll
  for (int tt = 0; tt < 2; ++tt) {
    int t = tp * 2 + tt;
    v4f acc = {0.f, 0.f, 0.f, 0.f};
#pragma unroll
    for (int kk = 0; kk < KK; ++kk) {
      v8s bf = *(const v8s*)(WTF + (size_t)(((t * KK + kk) * 4 + quad) * 16 + l15) * 8);
      acc = __builtin_amdgcn_mfma_f32_16x16x32_bf16(af[kk], bf, acc, 0, 0, 0);
    }
    float bias = b[t * 16 + l15];
#pragma unroll
    for (int i = 0; i < 4; ++i) {
      float o = fmaxf(acc[i] + bias, 0.f) * dr[i];
      sm[(rt * 16 + quad * 4 + i) * CP + t * 16 + l15] = f2bf(o);
    }
  }
  __syncthreads();

  // ---- phase 3: coalesced nontemporal C store ----
#pragma unroll
  for (int j = 0; j < 2; ++j) {
    int linear = j * 1024 + tid;
    int r = linear >> 5, ch = linear & 31;
    unsigned long long v = *(const unsigned long long*)&sm[r * CP + ch * 4];
    int row = row0 + r;
    if (row < N)
      __builtin_nontemporal_store(v, (unsigned long long*)C + (size_t)row * 32 + ch);
  }
}

// ---------------- layer 3: fused aggregate + GEMM + pool-atomics ----------------
__global__ __launch_bounds__(1024, 8) void k_fused_pool(const unsigned short* __restrict__ hin,
                                                        const unsigned short* __restrict__ WTF,
                                                        const float* __restrict__ b,
                                                        const int* __restrict__ rowptr,
                                                        const int* __restrict__ col,
                                                        const float* __restrict__ dinv,
                                                        const int* __restrict__ batch,
                                                        float* __restrict__ out, int N) {
  constexpr int KK = 4, KP = 136, CP = 132;
  constexpr int SMSZ = 64 * KP;
  __shared__ __align__(16) unsigned short sm[SMSZ];
  __shared__ int sbatch[64];

  int tid = threadIdx.x;
  int l16 = tid & 15;
  int nl = tid >> 4;
  int row0 = blockIdx.x * 64;
  int node = row0 + nl;

  if (tid < 64) sbatch[tid] = (row0 + tid < N) ? batch[row0 + tid] : -1;

  // ---- phase 1 ----
  {
    const uint4* hp = (const uint4*)hin;
    float a0 = 0.f, a1 = 0.f, a2 = 0.f, a3 = 0.f, a4 = 0.f, a5 = 0.f, a6 = 0.f, a7 = 0.f;
    if (node < N) {
      uint4 u = hp[(size_t)node * 16 + l16];
      a0 = bflo(u.x); a1 = bfhi(u.x);
      a2 = bflo(u.y); a3 = bfhi(u.y);
      a4 = bflo(u.z); a5 = bfhi(u.z);
      a6 = bflo(u.w); a7 = bfhi(u.w);
      int e0 = rowptr[node], e1 = rowptr[node + 1];
      int e = e0;
      for (; e + 2 <= e1; e += 2) {
        int c0 = col[e], c1 = col[e + 1];
        uint4 v0 = hp[(size_t)c0 * 16 + l16];
        uint4 v1 = hp[(size_t)c1 * 16 + l16];
        a0 += bflo(v0.x); a1 += bfhi(v0.x);
        a2 += bflo(v0.y); a3 += bfhi(v0.y);
        a4 += bflo(v0.z); a5 += bfhi(v0.z);
        a6 += bflo(v0.w); a7 += bfhi(v0.w);
        a0 += bflo(v1.x); a1 += bfhi(v1.x);
        a2 += bflo(v1.y); a3 += bfhi(v1.y);
        a4 += bflo(v1.z); a5 += bfhi(v1.z);
        a6 += bflo(v1.w); a7 += bfhi(v1.w);
      }
      if (e < e1) {
        uint4 v0 = hp[(size_t)col[e] * 16 + l16];
        a0 += bflo(v0.x); a1 += bfhi(v0.x);
        a2 += bflo(v0.y); a3 += bfhi(v0.y);
        a4 += bflo(v0.z); a5 += bfhi(v0.z);
        a6 += bflo(v0.w); a7 += bfhi(v0.w);
      }
      float di = dinv[node];
      a0 *= di; a1 *= di; a2 *= di; a3 *= di;
      a4 *= di; a5 *= di; a6 *= di; a7 *= di;
    }
    uint4 o;
    o.x = (unsigned int)f2bf(a0) | ((unsigned int)f2bf(a1) << 16);
    o.y = (unsigned int)f2bf(a2) | ((unsigned int)f2bf(a3) << 16);
    o.z = (unsigned int)f2bf(a4) | ((unsigned int)f2bf(a5) << 16);
    o.w = (unsigned int)f2bf(a6) | ((unsigned int)f2bf(a7) << 16);
    *(uint4*)&sm[nl * KP + l16 * 8] = o;
  }
  __syncthreads();

  // ---- phase 2 (no epilogue scaling: pool needs raw h3) ----
  int wv = tid >> 6, lane = tid & 63, quad = lane >> 4, l15 = lane & 15;
  int rt = wv & 3, tp = wv >> 2;
  v8s af[KK];
#pragma unroll
  for (int kk = 0; kk < KK; ++kk)
    af[kk] = *(const v8s*)&sm[(rt * 16 + l15) * KP + kk * 32 + quad * 8];
  __syncthreads();

#pragma unroll
  for (int tt = 0; tt < 2; ++tt) {
    int t = tp * 2 + tt;
    v4f acc = {0.f, 0.f, 0.f, 0.f};
#pragma unroll
    for (int kk = 0; kk < KK; ++kk) {
      v8s bf = *(const v8s*)(WTF + (size_t)(((t * KK + kk) * 4 + quad) * 16 + l15) * 8);
      acc = __builtin_amdgcn_mfma_f32_16x16x32_bf16(af[kk], bf, acc, 0, 0, 0);
    }
    float bias = b[t * 16 + l15];
#pragma unroll
    for (int i = 0; i < 4; ++i) {
      float o = fmaxf(acc[i] + bias, 0.f);
      sm[(rt * 16 + quad * 4 + i) * CP + t * 16 + l15] = f2bf(o);
    }
  }
  __syncthreads();

  // ---- phase 3: segment-sum the 64 sorted rows, atomicAdd partials ----
  int f = tid & 127;
  int grp = tid >> 7;
  float run = 0.f;
  int cur = -1;
#pragma unroll
  for (int j = 0; j < 8; ++j) {
    int r = grp * 8 + j;
    int g = sbatch[r];
    if (g != cur) {
      if (cur >= 0) atomicAdd(&out[(size_t)cur * 128 + f], run);
      run = 0.f; cur = g;
    }
    if (g >= 0) run += bf2f(sm[r * CP + f]);
  }
  if (cur >= 0) atomicAdd(&out[(size_t)cur * 128 + f], run);
}

// divide pooled sums by segment counts
__global__ void k_finalize(float* __restrict__ out, const int* __restrict__ gstart, int G) {
  int idx = blockIdx.x * blockDim.x + threadIdx.x;
  if (idx >= G * 128) return;
  int g = idx >> 7;
  float cnt = (float)(gstart[g + 1] - gstart[g]);
  out[idx] = out[idx] / fmaxf(cnt, 1.f);
}

extern "C" void kernel_launch(void* const* d_in, const int* in_sizes, int n_in,
                              void* d_out, int out_size, void* d_ws, size_t ws_size,
                              hipStream_t stream) {
  const float* x  = (const float*)d_in[0];
  const int* ei   = (const int*)d_in[1];
  const int* batch = (const int*)d_in[2];
  const float* W1 = (const float*)d_in[3];
  const float* b1 = (const float*)d_in[4];
  const float* W2 = (const float*)d_in[5];
  const float* b2 = (const float*)d_in[6];
  const float* W3 = (const float*)d_in[7];
  const float* b3 = (const float*)d_in[8];
  float* out = (float*)d_out;
  int N = in_sizes[2];
  int E = in_sizes[1] / 2;
  int G = out_size / HD;
  const int* src = ei;
  const int* dst = ei + E;

  size_t off = 0;
  char* ws = (char*)d_ws;
  auto alloc = [&](size_t bytes) -> void* {
    void* p = ws + off;
    off += (bytes + 255) & ~(size_t)255;
    return p;
  };
  int*   deg    = (int*)alloc((size_t)N * 4);
  float* dinv   = (float*)alloc((size_t)N * 4);
  int*   rowptr = (int*)alloc((size_t)(N + 1) * 4);
  int*   cursor = (int*)alloc((size_t)N * 4);
  int*   col    = (int*)alloc((size_t)E * 4);
  int*   bsum   = (int*)alloc(256 * 4);
  int*   boff   = (int*)alloc(256 * 4);
  int*   gstart = (int*)alloc((size_t)(G + 1) * 4);
  unsigned short* xb  = (unsigned short*)alloc((size_t)N * 32 * 2);
  unsigned short* hA  = (unsigned short*)alloc((size_t)N * HD * 2);
  unsigned short* hB  = (unsigned short*)alloc((size_t)N * HD * 2);
  unsigned short* W1F = (unsigned short*)alloc(4096 * 2);
  unsigned short* W2F = (unsigned short*)alloc(16384 * 2);
  unsigned short* W3F = (unsigned short*)alloc(16384 * 2);
  (void)ws_size; (void)n_in;

  int nb1024 = (N + 1023) / 1024;
  hipMemsetAsync(deg, 0, (size_t)N * 4, stream);
  hipMemsetAsync(out, 0, (size_t)out_size * 4, stream);
  k_degree<<<(E + 255) / 256, 256, 0, stream>>>(dst, deg, E);
  k_scan1<<<nb1024, 256, 0, stream>>>(deg, bsum, N);
  k_scan2<<<1, 256, 0, stream>>>(bsum, boff, nb1024);
  k_scan3<<<nb1024, 256, 0, stream>>>(deg, boff, rowptr, cursor, dinv, N);

  int SB = (E + 255) / 256;
  int XB = (N * 32 + 255) / 256;
  int WB = 144;
  int BB = (N + 255) / 256;
  k_prep<<<SB + XB + WB + BB, 256, 0, stream>>>(src, dst, cursor, col, E,
                                                x, dinv, xb, N,
                                                W1, W2, W3, W1F, W2F, W3F,
                                                batch, gstart, G, SB, XB, WB);

  int fusedBlocks = (N + 63) / 64;
  k_fused<32><<<fusedBlocks, 1024, 0, stream>>>(xb, W1F, b1, rowptr, col, dinv, hA, N);
  k_fused<128><<<fusedBlocks, 1024, 0, stream>>>(hA, W2F, b2, rowptr, col, dinv, hB, N);
  k_fused_pool<<<fusedBlocks, 1024, 0, stream>>>(hB, W3F, b3, rowptr, col, dinv, batch, out, N);
  k_finalize<<<(G * 128 + 255) / 256, 256, 0, stream>>>(out, gstart, G);
}

// Round 13
// 298.803 us; speedup vs baseline: 1.0766x; 1.0574x over previous
//
#include <hip/hip_runtime.h>

// 3-layer GCN + mean pool. bf16 storage / MFMA GEMM / fp32 accumulate.
// R13: R12 minus the nontemporal-store mistake (h IS re-read by the next
// layer; NT evicted it from L2), plus de-atomicized CSR scatter:
// k_degree records eord[e]=atomicAdd(deg[dst],1); scatter writes
// col[rowptr[dst]+eord[e]] with no cursor atomics (cursor deleted).
// Fused gather kernels sit at the measured ~60 us/layer random-gather
// service floor (R9: occupancy-insensitive; R12: write-insensitive).

#define DIN 30
#define HD  128

typedef __attribute__((ext_vector_type(8))) short v8s;
typedef __attribute__((ext_vector_type(4))) float v4f;

static __device__ __forceinline__ unsigned short f2bf(float f) {
  unsigned int u = __float_as_uint(f);
  u += 0x7fffu + ((u >> 16) & 1u);   // RNE
  return (unsigned short)(u >> 16);
}
static __device__ __forceinline__ float bf2f(unsigned short s) {
  return __uint_as_float(((unsigned int)s) << 16);
}
static __device__ __forceinline__ float bflo(unsigned int u) {
  return __uint_as_float(u << 16);
}
static __device__ __forceinline__ float bfhi(unsigned int u) {
  return __uint_as_float(u & 0xffff0000u);
}

// ---------------- preprocessing ----------------
// degree + edge-order (position of edge within its destination's bucket)
__global__ void k_degree(const int* __restrict__ dst, int* __restrict__ deg,
                         int* __restrict__ eord, int E) {
  int e = blockIdx.x * blockDim.x + threadIdx.x;
  if (e < E) eord[e] = atomicAdd(&deg[dst[e]], 1);
}

__global__ void k_scan1(const int* __restrict__ deg, int* __restrict__ bsum, int N) {
  __shared__ int s[256];
  int tid = threadIdx.x;
  int base = blockIdx.x * 1024 + tid * 4;
  int t = 0;
#pragma unroll
  for (int j = 0; j < 4; ++j) { int idx = base + j; if (idx < N) t += deg[idx]; }
  s[tid] = t; __syncthreads();
  for (int d = 128; d > 0; d >>= 1) { if (tid < d) s[tid] += s[tid + d]; __syncthreads(); }
  if (tid == 0) bsum[blockIdx.x] = s[0];
}

__global__ void k_scan2(const int* __restrict__ bsum, int* __restrict__ boff, int nb) {
  __shared__ int s[256];
  int tid = threadIdx.x;
  int v = (tid < nb) ? bsum[tid] : 0;
  s[tid] = v; __syncthreads();
  for (int d = 1; d < 256; d <<= 1) {
    int t = (tid >= d) ? s[tid - d] : 0;
    __syncthreads();
    s[tid] += t;
    __syncthreads();
  }
  boff[tid] = s[tid] - v;
}

// scan3 + dinv fused (no cursor writes anymore)
__global__ void k_scan3(const int* __restrict__ deg, const int* __restrict__ boff,
                        int* __restrict__ rowptr, float* __restrict__ dinv, int N) {
  __shared__ int s[256];
  int tid = threadIdx.x;
  int base = blockIdx.x * 1024 + tid * 4;
  int v[4]; int t = 0;
#pragma unroll
  for (int j = 0; j < 4; ++j) { int idx = base + j; v[j] = (idx < N) ? deg[idx] : 0; t += v[j]; }
  s[tid] = t; __syncthreads();
  for (int d = 1; d < 256; d <<= 1) {
    int u = (tid >= d) ? s[tid - d] : 0;
    __syncthreads();
    s[tid] += u;
    __syncthreads();
  }
  int run = boff[blockIdx.x] + s[tid] - t;
#pragma unroll
  for (int j = 0; j < 4; ++j) {
    int idx = base + j;
    if (idx < N) {
      rowptr[idx] = run;
      dinv[idx] = rsqrtf((float)(1 + v[j]));
    }
    run += v[j];
    if (idx == N - 1) rowptr[N] = run;
  }
}

// fragment-major weight pack helper
static __device__ __forceinline__ void wtf_one(const float* __restrict__ W,
                                               unsigned short* __restrict__ WTF,
                                               int idx, int Kreal, int KK) {
  int j = idx & 7;
  int c = idx >> 3;
  int l15 = c & 15;
  int quad = (c >> 4) & 3;
  int kk = (c >> 6) % KK;
  int t = c / (64 * KK);
  int k = kk * 32 + quad * 8 + j;
  int n = t * 16 + l15;
  WTF[idx] = (k < Kreal) ? f2bf(W[k * 128 + n]) : (unsigned short)0;
}

// merged post-scan prep: atomic-free CSR scatter | xcast | wtf | bounds
__global__ void k_prep(const int* __restrict__ src, const int* __restrict__ dst,
                       const int* __restrict__ rowptr, const int* __restrict__ eord,
                       int* __restrict__ col, int E,
                       const float* __restrict__ x, const float* __restrict__ dinv,
                       unsigned short* __restrict__ xb, int N,
                       const float* __restrict__ W1, const float* __restrict__ W2,
                       const float* __restrict__ W3,
                       unsigned short* __restrict__ W1F, unsigned short* __restrict__ W2F,
                       unsigned short* __restrict__ W3F,
                       const int* __restrict__ batch, int* __restrict__ gstart, int G,
                       int SB, int XB, int WB) {
  int blk = blockIdx.x;
  if (blk < SB) {
    int e = blk * 256 + threadIdx.x;
    if (e < E) col[rowptr[dst[e]] + eord[e]] = src[e];
  } else if (blk < SB + XB) {
    int idx = (blk - SB) * 256 + threadIdx.x;
    if (idx < N * 32) {
      int n = idx >> 5, f = idx & 31;
      float v = (f < DIN) ? x[(size_t)n * DIN + f] * dinv[n] : 0.f;
      xb[idx] = f2bf(v);
    }
  } else if (blk < SB + XB + WB) {
    int idx = (blk - SB - XB) * 256 + threadIdx.x;
    if (idx < 4096) wtf_one(W1, W1F, idx, DIN, 1);
    else if (idx < 20480) wtf_one(W2, W2F, idx - 4096, 128, 4);
    else if (idx < 36864) wtf_one(W3, W3F, idx - 20480, 128, 4);
  } else {
    int i = (blk - SB - XB - WB) * 256 + threadIdx.x;
    if (i >= N) return;
    int b = batch[i];
    int prev = (i == 0) ? -1 : batch[i - 1];
    for (int g = prev + 1; g <= b; ++g) gstart[g] = i;
    if (i == N - 1)
      for (int g = b + 1; g <= G; ++g) gstart[g] = N;
  }
}

// ---------------- fused aggregate + MFMA GEMM (layers 1,2) ----------------
template <int K>
__global__ __launch_bounds__(1024, 8) void k_fused(const unsigned short* __restrict__ hin,
                                                   const unsigned short* __restrict__ WTF,
                                                   const float* __restrict__ b,
                                                   const int* __restrict__ rowptr,
                                                   const int* __restrict__ col,
                                                   const float* __restrict__ dinv,
                                                   unsigned short* __restrict__ C, int N) {
  constexpr int KK = K / 32;
  constexpr int KP = (K == 128) ? 136 : 40;
  constexpr int CP = 132;
  constexpr int SMSZ = (64 * KP > 64 * CP) ? 64 * KP : 64 * CP;
  __shared__ __align__(16) unsigned short sm[SMSZ];

  int tid = threadIdx.x;
  int l16 = tid & 15;
  int nl = tid >> 4;
  int row0 = blockIdx.x * 64;
  int node = row0 + nl;

  // ---- phase 1: agg = dinv[node] * (sum h'[col] + h'[node]) into LDS ----
  if (K == 32) {
    const unsigned int* hp = (const unsigned int*)hin;
    float a0 = 0.f, a1 = 0.f;
    if (node < N) {
      unsigned int u = hp[(size_t)node * 16 + l16];
      a0 = bflo(u); a1 = bfhi(u);
      int e0 = rowptr[node], e1 = rowptr[node + 1];
      int e = e0;
      for (; e + 2 <= e1; e += 2) {
        int c0 = col[e], c1 = col[e + 1];
        unsigned int v0 = hp[(size_t)c0 * 16 + l16];
        unsigned int v1 = hp[(size_t)c1 * 16 + l16];
        a0 += bflo(v0); a1 += bfhi(v0);
        a0 += bflo(v1); a1 += bfhi(v1);
      }
      if (e < e1) {
        unsigned int v0 = hp[(size_t)col[e] * 16 + l16];
        a0 += bflo(v0); a1 += bfhi(v0);
      }
      float di = dinv[node];
      a0 *= di; a1 *= di;
    }
    *(unsigned int*)&sm[nl * KP + l16 * 2] =
        (unsigned int)f2bf(a0) | ((unsigned int)f2bf(a1) << 16);
  } else {
    const uint4* hp = (const uint4*)hin;
    float a0 = 0.f, a1 = 0.f, a2 = 0.f, a3 = 0.f, a4 = 0.f, a5 = 0.f, a6 = 0.f, a7 = 0.f;
    if (node < N) {
      uint4 u = hp[(size_t)node * 16 + l16];
      a0 = bflo(u.x); a1 = bfhi(u.x);
      a2 = bflo(u.y); a3 = bfhi(u.y);
      a4 = bflo(u.z); a5 = bfhi(u.z);
      a6 = bflo(u.w); a7 = bfhi(u.w);
      int e0 = rowptr[node], e1 = rowptr[node + 1];
      int e = e0;
      for (; e + 2 <= e1; e += 2) {
        int c0 = col[e], c1 = col[e + 1];
        uint4 v0 = hp[(size_t)c0 * 16 + l16];
        uint4 v1 = hp[(size_t)c1 * 16 + l16];
        a0 += bflo(v0.x); a1 += bfhi(v0.x);
        a2 += bflo(v0.y); a3 += bfhi(v0.y);
        a4 += bflo(v0.z); a5 += bfhi(v0.z);
        a6 += bflo(v0.w); a7 += bfhi(v0.w);
        a0 += bflo(v1.x); a1 += bfhi(v1.x);
        a2 += bflo(v1.y); a3 += bfhi(v1.y);
        a4 += bflo(v1.z); a5 += bfhi(v1.z);
        a6 += bflo(v1.w); a7 += bfhi(v1.w);
      }
      if (e < e1) {
        uint4 v0 = hp[(size_t)col[e] * 16 + l16];
        a0 += bflo(v0.x); a1 += bfhi(v0.x);
        a2 += bflo(v0.y); a3 += bfhi(v0.y);
        a4 += bflo(v0.z); a5 += bfhi(v0.z);
        a6 += bflo(v0.w); a7 += bfhi(v0.w);
      }
      float di = dinv[node];
      a0 *= di; a1 *= di; a2 *= di; a3 *= di;
      a4 *= di; a5 *= di; a6 *= di; a7 *= di;
    }
    uint4 o;
    o.x = (unsigned int)f2bf(a0) | ((unsigned int)f2bf(a1) << 16);
    o.y = (unsigned int)f2bf(a2) | ((unsigned int)f2bf(a3) << 16);
    o.z = (unsigned int)f2bf(a4) | ((unsigned int)f2bf(a5) << 16);
    o.w = (unsigned int)f2bf(a6) | ((unsigned int)f2bf(a7) << 16);
    *(uint4*)&sm[nl * KP + l16 * 8] = o;
  }
  __syncthreads();

  // ---- phase 2: A-frags from LDS; 16 waves = 4 row-tiles x 4 t-pairs ----
  int wv = tid >> 6, lane = tid & 63, quad = lane >> 4, l15 = lane & 15;
  int rt = wv & 3, tp = wv >> 2;
  v8s af[KK];
#pragma unroll
  for (int kk = 0; kk < KK; ++kk)
    af[kk] = *(const v8s*)&sm[(rt * 16 + l15) * KP + kk * 32 + quad * 8];
  __syncthreads();

  // hoisted next-layer pre-scale: dinv for this lane's 4 output rows
  int crow0 = row0 + rt * 16 + quad * 4;
  float dr[4];
  if (crow0 + 3 < N) {
    float4 d4 = *(const float4*)&dinv[crow0];
    dr[0] = d4.x; dr[1] = d4.y; dr[2] = d4.z; dr[3] = d4.w;
  } else {
#pragma unroll
    for (int i = 0; i < 4; ++i) dr[i] = (crow0 + i < N) ? dinv[crow0 + i] : 0.f;
  }

#pragma unroll
  for (int tt = 0; tt < 2; ++tt) {
    int t = tp * 2 + tt;
    v4f acc = {0.f, 0.f, 0.f, 0.f};
#pragma unroll
    for (int kk = 0; kk < KK; ++kk) {
      v8s bf = *(const v8s*)(WTF + (size_t)(((t * KK + kk) * 4 + quad) * 16 + l15) * 8);
      acc = __builtin_amdgcn_mfma_f32_16x16x32_bf16(af[kk], bf, acc, 0, 0, 0);
    }
    float bias = b[t * 16 + l15];
#pragma unroll
    for (int i = 0; i < 4; ++i) {
      float o = fmaxf(acc[i] + bias, 0.f) * dr[i];
      sm[(rt * 16 + quad * 4 + i) * CP + t * 16 + l15] = f2bf(o);
    }
  }
  __syncthreads();

  // ---- phase 3: coalesced C store ----
#pragma unroll
  for (int j = 0; j < 2; ++j) {
    int linear = j * 1024 + tid;
    int r = linear >> 5, ch = linear & 31;
    uint2 v = *(const uint2*)&sm[r * CP + ch * 4];
    int row = row0 + r;
    if (row < N) ((uint2*)C)[(size_t)row * 32 + ch] = v;
  }
}

// ---------------- layer 3: fused aggregate + GEMM + pool-atomics ----------------
__global__ __launch_bounds__(1024, 8) void k_fused_pool(const unsigned short* __restrict__ hin,
                                                        const unsigned short* __restrict__ WTF,
                                                        const float* __restrict__ b,
                                                        const int* __restrict__ rowptr,
                                                        const int* __restrict__ col,
                                                        const float* __restrict__ dinv,
                                                        const int* __restrict__ batch,
                                                        float* __restrict__ out, int N) {
  constexpr int KK = 4, KP = 136, CP = 132;
  constexpr int SMSZ = 64 * KP;
  __shared__ __align__(16) unsigned short sm[SMSZ];
  __shared__ int sbatch[64];

  int tid = threadIdx.x;
  int l16 = tid & 15;
  int nl = tid >> 4;
  int row0 = blockIdx.x * 64;
  int node = row0 + nl;

  if (tid < 64) sbatch[tid] = (row0 + tid < N) ? batch[row0 + tid] : -1;

  // ---- phase 1 ----
  {
    const uint4* hp = (const uint4*)hin;
    float a0 = 0.f, a1 = 0.f, a2 = 0.f, a3 = 0.f, a4 = 0.f, a5 = 0.f, a6 = 0.f, a7 = 0.f;
    if (node < N) {
      uint4 u = hp[(size_t)node * 16 + l16];
      a0 = bflo(u.x); a1 = bfhi(u.x);
      a2 = bflo(u.y); a3 = bfhi(u.y);
      a4 = bflo(u.z); a5 = bfhi(u.z);
      a6 = bflo(u.w); a7 = bfhi(u.w);
      int e0 = rowptr[node], e1 = rowptr[node + 1];
      int e = e0;
      for (; e + 2 <= e1; e += 2) {
        int c0 = col[e], c1 = col[e + 1];
        uint4 v0 = hp[(size_t)c0 * 16 + l16];
        uint4 v1 = hp[(size_t)c1 * 16 + l16];
        a0 += bflo(v0.x); a1 += bfhi(v0.x);
        a2 += bflo(v0.y); a3 += bfhi(v0.y);
        a4 += bflo(v0.z); a5 += bfhi(v0.z);
        a6 += bflo(v0.w); a7 += bfhi(v0.w);
        a0 += bflo(v1.x); a1 += bfhi(v1.x);
        a2 += bflo(v1.y); a3 += bfhi(v1.y);
        a4 += bflo(v1.z); a5 += bfhi(v1.z);
        a6 += bflo(v1.w); a7 += bfhi(v1.w);
      }
      if (e < e1) {
        uint4 v0 = hp[(size_t)col[e] * 16 + l16];
        a0 += bflo(v0.x); a1 += bfhi(v0.x);
        a2 += bflo(v0.y); a3 += bfhi(v0.y);
        a4 += bflo(v0.z); a5 += bfhi(v0.z);
        a6 += bflo(v0.w); a7 += bfhi(v0.w);
      }
      float di = dinv[node];
      a0 *= di; a1 *= di; a2 *= di; a3 *= di;
      a4 *= di; a5 *= di; a6 *= di; a7 *= di;
    }
    uint4 o;
    o.x = (unsigned int)f2bf(a0) | ((unsigned int)f2bf(a1) << 16);
    o.y = (unsigned int)f2bf(a2) | ((unsigned int)f2bf(a3) << 16);
    o.z = (unsigned int)f2bf(a4) | ((unsigned int)f2bf(a5) << 16);
    o.w = (unsigned int)f2bf(a6) | ((unsigned int)f2bf(a7) << 16);
    *(uint4*)&sm[nl * KP + l16 * 8] = o;
  }
  __syncthreads();

  // ---- phase 2 (no epilogue scaling: pool needs raw h3) ----
  int wv = tid >> 6, lane = tid & 63, quad = lane >> 4, l15 = lane & 15;
  int rt = wv & 3, tp = wv >> 2;
  v8s af[KK];
#pragma unroll
  for (int kk = 0; kk < KK; ++kk)
    af[kk] = *(const v8s*)&sm[(rt * 16 + l15) * KP + kk * 32 + quad * 8];
  __syncthreads();

#pragma unroll
  for (int tt = 0; tt < 2; ++tt) {
    int t = tp * 2 + tt;
    v4f acc = {0.f, 0.f, 0.f, 0.f};
#pragma unroll
    for (int kk = 0; kk < KK; ++kk) {
      v8s bf = *(const v8s*)(WTF + (size_t)(((t * KK + kk) * 4 + quad) * 16 + l15) * 8);
      acc = __builtin_amdgcn_mfma_f32_16x16x32_bf16(af[kk], bf, acc, 0, 0, 0);
    }
    float bias = b[t * 16 + l15];
#pragma unroll
    for (int i = 0; i < 4; ++i) {
      float o = fmaxf(acc[i] + bias, 0.f);
      sm[(rt * 16 + quad * 4 + i) * CP + t * 16 + l15] = f2bf(o);
    }
  }
  __syncthreads();

  // ---- phase 3: segment-sum the 64 sorted rows, atomicAdd partials ----
  int f = tid & 127;
  int grp = tid >> 7;
  float run = 0.f;
  int cur = -1;
#pragma unroll
  for (int j = 0; j < 8; ++j) {
    int r = grp * 8 + j;
    int g = sbatch[r];
    if (g != cur) {
      if (cur >= 0) atomicAdd(&out[(size_t)cur * 128 + f], run);
      run = 0.f; cur = g;
    }
    if (g >= 0) run += bf2f(sm[r * CP + f]);
  }
  if (cur >= 0) atomicAdd(&out[(size_t)cur * 128 + f], run);
}

// divide pooled sums by segment counts
__global__ void k_finalize(float* __restrict__ out, const int* __restrict__ gstart, int G) {
  int idx = blockIdx.x * blockDim.x + threadIdx.x;
  if (idx >= G * 128) return;
  int g = idx >> 7;
  float cnt = (float)(gstart[g + 1] - gstart[g]);
  out[idx] = out[idx] / fmaxf(cnt, 1.f);
}

extern "C" void kernel_launch(void* const* d_in, const int* in_sizes, int n_in,
                              void* d_out, int out_size, void* d_ws, size_t ws_size,
                              hipStream_t stream) {
  const float* x  = (const float*)d_in[0];
  const int* ei   = (const int*)d_in[1];
  const int* batch = (const int*)d_in[2];
  const float* W1 = (const float*)d_in[3];
  const float* b1 = (const float*)d_in[4];
  const float* W2 = (const float*)d_in[5];
  const float* b2 = (const float*)d_in[6];
  const float* W3 = (const float*)d_in[7];
  const float* b3 = (const float*)d_in[8];
  float* out = (float*)d_out;
  int N = in_sizes[2];
  int E = in_sizes[1] / 2;
  int G = out_size / HD;
  const int* src = ei;
  const int* dst = ei + E;

  size_t off = 0;
  char* ws = (char*)d_ws;
  auto alloc = [&](size_t bytes) -> void* {
    void* p = ws + off;
    off += (bytes + 255) & ~(size_t)255;
    return p;
  };
  int*   deg    = (int*)alloc((size_t)N * 4);
  float* dinv   = (float*)alloc((size_t)N * 4);
  int*   rowptr = (int*)alloc((size_t)(N + 1) * 4);
  int*   eord   = (int*)alloc((size_t)E * 4);
  int*   col    = (int*)alloc((size_t)E * 4);
  int*   bsum   = (int*)alloc(256 * 4);
  int*   boff   = (int*)alloc(256 * 4);
  int*   gstart = (int*)alloc((size_t)(G + 1) * 4);
  unsigned short* xb  = (unsigned short*)alloc((size_t)N * 32 * 2);
  unsigned short* hA  = (unsigned short*)alloc((size_t)N * HD * 2);
  unsigned short* hB  = (unsigned short*)alloc((size_t)N * HD * 2);
  unsigned short* W1F = (unsigned short*)alloc(4096 * 2);
  unsigned short* W2F = (unsigned short*)alloc(16384 * 2);
  unsigned short* W3F = (unsigned short*)alloc(16384 * 2);
  (void)ws_size; (void)n_in;

  int nb1024 = (N + 1023) / 1024;
  hipMemsetAsync(deg, 0, (size_t)N * 4, stream);
  hipMemsetAsync(out, 0, (size_t)out_size * 4, stream);
  k_degree<<<(E + 255) / 256, 256, 0, stream>>>(dst, deg, eord, E);
  k_scan1<<<nb1024, 256, 0, stream>>>(deg, bsum, N);
  k_scan2<<<1, 256, 0, stream>>>(bsum, boff, nb1024);
  k_scan3<<<nb1024, 256, 0, stream>>>(deg, boff, rowptr, dinv, N);

  int SB = (E + 255) / 256;
  int XB = (N * 32 + 255) / 256;
  int WB = 144;
  int BB = (N + 255) / 256;
  k_prep<<<SB + XB + WB + BB, 256, 0, stream>>>(src, dst, rowptr, eord, col, E,
                                                x, dinv, xb, N,
                                                W1, W2, W3, W1F, W2F, W3F,
                                                batch, gstart, G, SB, XB, WB);

  int fusedBlocks = (N + 63) / 64;
  k_fused<32><<<fusedBlocks, 1024, 0, stream>>>(xb, W1F, b1, rowptr, col, dinv, hA, N);
  k_fused<128><<<fusedBlocks, 1024, 0, stream>>>(hA, W2F, b2, rowptr, col, dinv, hB, N);
  k_fused_pool<<<fusedBlocks, 1024, 0, stream>>>(hB, W3F, b3, rowptr, col, dinv, batch, out, N);
  k_finalize<<<(G * 128 + 255) / 256, 256, 0, stream>>>(out, gstart, G);
}

// Round 14
// 295.388 us; speedup vs baseline: 1.0890x; 1.0116x over previous
//
#include <hip/hip_runtime.h>

// 3-layer GCN + mean pool. bf16 storage / MFMA GEMM / fp32 accumulate.
// R14: dispatch dieting. R13 fused kernels untouched (at the measured
// ~60 us/layer random-gather service wall: R9 occupancy-insensitive,
// R12 write-insensitive). Changes:
//  - scan1/2/3 -> single decoupled-lookback scan dispatch (flag-in-value)
//  - out-zeroing folded into k_prep (uint4 stores)
//  - one memset covers deg + scan buffer

#define DIN 30
#define HD  128

typedef __attribute__((ext_vector_type(8))) short v8s;
typedef __attribute__((ext_vector_type(4))) float v4f;

static __device__ __forceinline__ unsigned short f2bf(float f) {
  unsigned int u = __float_as_uint(f);
  u += 0x7fffu + ((u >> 16) & 1u);   // RNE
  return (unsigned short)(u >> 16);
}
static __device__ __forceinline__ float bf2f(unsigned short s) {
  return __uint_as_float(((unsigned int)s) << 16);
}
static __device__ __forceinline__ float bflo(unsigned int u) {
  return __uint_as_float(u << 16);
}
static __device__ __forceinline__ float bfhi(unsigned int u) {
  return __uint_as_float(u & 0xffff0000u);
}

// ---------------- preprocessing ----------------
// degree + edge-order (position of edge within its destination's bucket)
__global__ void k_degree(const int* __restrict__ dst, int* __restrict__ deg,
                         int* __restrict__ eord, int E) {
  int e = blockIdx.x * blockDim.x + threadIdx.x;
  if (e < E) eord[e] = atomicAdd(&deg[dst[e]], 1);
}

// single-dispatch exclusive scan (decoupled lookback, flag bit 31) + dinv.
// scanbuf[NB] must be zeroed. 256 threads x 4 elems per block.
__global__ void k_scan(const int* __restrict__ deg, int* __restrict__ scanbuf,
                       int* __restrict__ rowptr, float* __restrict__ dinv, int N) {
  __shared__ int s[256];
  __shared__ int sbase;
  int bid = blockIdx.x, tid = threadIdx.x;
  int base = bid * 1024 + tid * 4;
  int v[4]; int t = 0;
#pragma unroll
  for (int j = 0; j < 4; ++j) { int idx = base + j; v[j] = (idx < N) ? deg[idx] : 0; t += v[j]; }
  s[tid] = t; __syncthreads();
  for (int d = 1; d < 256; d <<= 1) {
    int u = (tid >= d) ? s[tid - d] : 0;
    __syncthreads();
    s[tid] += u;
    __syncthreads();
  }
  int myexcl = s[tid] - t;           // exclusive prefix within block
  int blocktotal = s[255];
  if (tid == 0) atomicExch(&scanbuf[bid], blocktotal | 0x80000000);

  // parallel lookback: threads spin on predecessor flags
  int pre = 0;
  for (int p = tid; p < bid; p += 256) {
    int val;
    do { val = atomicAdd(&scanbuf[p], 0); } while (!(val & 0x80000000));
    pre += val & 0x7fffffff;
  }
  __syncthreads();                   // s[] free for reuse
  s[tid] = pre; __syncthreads();
  for (int d = 128; d > 0; d >>= 1) { if (tid < d) s[tid] += s[tid + d]; __syncthreads(); }
  if (tid == 0) sbase = s[0];
  __syncthreads();

  int run = sbase + myexcl;
#pragma unroll
  for (int j = 0; j < 4; ++j) {
    int idx = base + j;
    if (idx < N) {
      rowptr[idx] = run;
      dinv[idx] = rsqrtf((float)(1 + v[j]));
    }
    run += v[j];
    if (idx == N - 1) rowptr[N] = run;
  }
}

// fragment-major weight pack helper
static __device__ __forceinline__ void wtf_one(const float* __restrict__ W,
                                               unsigned short* __restrict__ WTF,
                                               int idx, int Kreal, int KK) {
  int j = idx & 7;
  int c = idx >> 3;
  int l15 = c & 15;
  int quad = (c >> 4) & 3;
  int kk = (c >> 6) % KK;
  int t = c / (64 * KK);
  int k = kk * 32 + quad * 8 + j;
  int n = t * 16 + l15;
  WTF[idx] = (k < Kreal) ? f2bf(W[k * 128 + n]) : (unsigned short)0;
}

// merged prep: atomic-free CSR scatter | xcast | wtf | bounds | out-zero
__global__ void k_prep(const int* __restrict__ src, const int* __restrict__ dst,
                       const int* __restrict__ rowptr, const int* __restrict__ eord,
                       int* __restrict__ col, int E,
                       const float* __restrict__ x, const float* __restrict__ dinv,
                       unsigned short* __restrict__ xb, int N,
                       const float* __restrict__ W1, const float* __restrict__ W2,
                       const float* __restrict__ W3,
                       unsigned short* __restrict__ W1F, unsigned short* __restrict__ W2F,
                       unsigned short* __restrict__ W3F,
                       const int* __restrict__ batch, int* __restrict__ gstart, int G,
                       float* __restrict__ out,
                       int SB, int XB, int WB, int BB) {
  int blk = blockIdx.x;
  if (blk < SB) {
    int e = blk * 256 + threadIdx.x;
    if (e < E) col[rowptr[dst[e]] + eord[e]] = src[e];
  } else if (blk < SB + XB) {
    int idx = (blk - SB) * 256 + threadIdx.x;
    if (idx < N * 32) {
      int n = idx >> 5, f = idx & 31;
      float v = (f < DIN) ? x[(size_t)n * DIN + f] * dinv[n] : 0.f;
      xb[idx] = f2bf(v);
    }
  } else if (blk < SB + XB + WB) {
    int idx = (blk - SB - XB) * 256 + threadIdx.x;
    if (idx < 4096) wtf_one(W1, W1F, idx, DIN, 1);
    else if (idx < 20480) wtf_one(W2, W2F, idx - 4096, 128, 4);
    else if (idx < 36864) wtf_one(W3, W3F, idx - 20480, 128, 4);
  } else if (blk < SB + XB + WB + BB) {
    int i = (blk - SB - XB - WB) * 256 + threadIdx.x;
    if (i >= N) return;
    int b = batch[i];
    int prev = (i == 0) ? -1 : batch[i - 1];
    for (int g = prev + 1; g <= b; ++g) gstart[g] = i;
    if (i == N - 1)
      for (int g = b + 1; g <= G; ++g) gstart[g] = N;
  } else {
    // zero out[] : G*128 floats, float4 per thread
    int idx = (blk - SB - XB - WB - BB) * 256 + threadIdx.x;
    if (idx < G * 32)
      ((float4*)out)[idx] = make_float4(0.f, 0.f, 0.f, 0.f);
  }
}

// ---------------- fused aggregate + MFMA GEMM (layers 1,2) ----------------
template <int K>
__global__ __launch_bounds__(1024, 8) void k_fused(const unsigned short* __restrict__ hin,
                                                   const unsigned short* __restrict__ WTF,
                                                   const float* __restrict__ b,
                                                   const int* __restrict__ rowptr,
                                                   const int* __restrict__ col,
                                                   const float* __restrict__ dinv,
                                                   unsigned short* __restrict__ C, int N) {
  constexpr int KK = K / 32;
  constexpr int KP = (K == 128) ? 136 : 40;
  constexpr int CP = 132;
  constexpr int SMSZ = (64 * KP > 64 * CP) ? 64 * KP : 64 * CP;
  __shared__ __align__(16) unsigned short sm[SMSZ];

  int tid = threadIdx.x;
  int l16 = tid & 15;
  int nl = tid >> 4;
  int row0 = blockIdx.x * 64;
  int node = row0 + nl;

  // ---- phase 1: agg = dinv[node] * (sum h'[col] + h'[node]) into LDS ----
  if (K == 32) {
    const unsigned int* hp = (const unsigned int*)hin;
    float a0 = 0.f, a1 = 0.f;
    if (node < N) {
      unsigned int u = hp[(size_t)node * 16 + l16];
      a0 = bflo(u); a1 = bfhi(u);
      int e0 = rowptr[node], e1 = rowptr[node + 1];
      int e = e0;
      for (; e + 2 <= e1; e += 2) {
        int c0 = col[e], c1 = col[e + 1];
        unsigned int v0 = hp[(size_t)c0 * 16 + l16];
        unsigned int v1 = hp[(size_t)c1 * 16 + l16];
        a0 += bflo(v0); a1 += bfhi(v0);
        a0 += bflo(v1); a1 += bfhi(v1);
      }
      if (e < e1) {
        unsigned int v0 = hp[(size_t)col[e] * 16 + l16];
        a0 += bflo(v0); a1 += bfhi(v0);
      }
      float di = dinv[node];
      a0 *= di; a1 *= di;
    }
    *(unsigned int*)&sm[nl * KP + l16 * 2] =
        (unsigned int)f2bf(a0) | ((unsigned int)f2bf(a1) << 16);
  } else {
    const uint4* hp = (const uint4*)hin;
    float a0 = 0.f, a1 = 0.f, a2 = 0.f, a3 = 0.f, a4 = 0.f, a5 = 0.f, a6 = 0.f, a7 = 0.f;
    if (node < N) {
      uint4 u = hp[(size_t)node * 16 + l16];
      a0 = bflo(u.x); a1 = bfhi(u.x);
      a2 = bflo(u.y); a3 = bfhi(u.y);
      a4 = bflo(u.z); a5 = bfhi(u.z);
      a6 = bflo(u.w); a7 = bfhi(u.w);
      int e0 = rowptr[node], e1 = rowptr[node + 1];
      int e = e0;
      for (; e + 2 <= e1; e += 2) {
        int c0 = col[e], c1 = col[e + 1];
        uint4 v0 = hp[(size_t)c0 * 16 + l16];
        uint4 v1 = hp[(size_t)c1 * 16 + l16];
        a0 += bflo(v0.x); a1 += bfhi(v0.x);
        a2 += bflo(v0.y); a3 += bfhi(v0.y);
        a4 += bflo(v0.z); a5 += bfhi(v0.z);
        a6 += bflo(v0.w); a7 += bfhi(v0.w);
        a0 += bflo(v1.x); a1 += bfhi(v1.x);
        a2 += bflo(v1.y); a3 += bfhi(v1.y);
        a4 += bflo(v1.z); a5 += bfhi(v1.z);
        a6 += bflo(v1.w); a7 += bfhi(v1.w);
      }
      if (e < e1) {
        uint4 v0 = hp[(size_t)col[e] * 16 + l16];
        a0 += bflo(v0.x); a1 += bfhi(v0.x);
        a2 += bflo(v0.y); a3 += bfhi(v0.y);
        a4 += bflo(v0.z); a5 += bfhi(v0.z);
        a6 += bflo(v0.w); a7 += bfhi(v0.w);
      }
      float di = dinv[node];
      a0 *= di; a1 *= di; a2 *= di; a3 *= di;
      a4 *= di; a5 *= di; a6 *= di; a7 *= di;
    }
    uint4 o;
    o.x = (unsigned int)f2bf(a0) | ((unsigned int)f2bf(a1) << 16);
    o.y = (unsigned int)f2bf(a2) | ((unsigned int)f2bf(a3) << 16);
    o.z = (unsigned int)f2bf(a4) | ((unsigned int)f2bf(a5) << 16);
    o.w = (unsigned int)f2bf(a6) | ((unsigned int)f2bf(a7) << 16);
    *(uint4*)&sm[nl * KP + l16 * 8] = o;
  }
  __syncthreads();

  // ---- phase 2: A-frags from LDS; 16 waves = 4 row-tiles x 4 t-pairs ----
  int wv = tid >> 6, lane = tid & 63, quad = lane >> 4, l15 = lane & 15;
  int rt = wv & 3, tp = wv >> 2;
  v8s af[KK];
#pragma unroll
  for (int kk = 0; kk < KK; ++kk)
    af[kk] = *(const v8s*)&sm[(rt * 16 + l15) * KP + kk * 32 + quad * 8];
  __syncthreads();

  // hoisted next-layer pre-scale: dinv for this lane's 4 output rows
  int crow0 = row0 + rt * 16 + quad * 4;
  float dr[4];
  if (crow0 + 3 < N) {
    float4 d4 = *(const float4*)&dinv[crow0];
    dr[0] = d4.x; dr[1] = d4.y; dr[2] = d4.z; dr[3] = d4.w;
  } else {
#pragma unroll
    for (int i = 0; i < 4; ++i) dr[i] = (crow0 + i < N) ? dinv[crow0 + i] : 0.f;
  }

#pragma unroll
  for (int tt = 0; tt < 2; ++tt) {
    int t = tp * 2 + tt;
    v4f acc = {0.f, 0.f, 0.f, 0.f};
#pragma unroll
    for (int kk = 0; kk < KK; ++kk) {
      v8s bf = *(const v8s*)(WTF + (size_t)(((t * KK + kk) * 4 + quad) * 16 + l15) * 8);
      acc = __builtin_amdgcn_mfma_f32_16x16x32_bf16(af[kk], bf, acc, 0, 0, 0);
    }
    float bias = b[t * 16 + l15];
#pragma unroll
    for (int i = 0; i < 4; ++i) {
      float o = fmaxf(acc[i] + bias, 0.f) * dr[i];
      sm[(rt * 16 + quad * 4 + i) * CP + t * 16 + l15] = f2bf(o);
    }
  }
  __syncthreads();

  // ---- phase 3: coalesced C store ----
#pragma unroll
  for (int j = 0; j < 2; ++j) {
    int linear = j * 1024 + tid;
    int r = linear >> 5, ch = linear & 31;
    uint2 v = *(const uint2*)&sm[r * CP + ch * 4];
    int row = row0 + r;
    if (row < N) ((uint2*)C)[(size_t)row * 32 + ch] = v;
  }
}

// ---------------- layer 3: fused aggregate + GEMM + pool-atomics ----------------
__global__ __launch_bounds__(1024, 8) void k_fused_pool(const unsigned short* __restrict__ hin,
                                                        const unsigned short* __restrict__ WTF,
                                                        const float* __restrict__ b,
                                                        const int* __restrict__ rowptr,
                                                        const int* __restrict__ col,
                                                        const float* __restrict__ dinv,
                                                        const int* __restrict__ batch,
                                                        float* __restrict__ out, int N) {
  constexpr int KK = 4, KP = 136, CP = 132;
  constexpr int SMSZ = 64 * KP;
  __shared__ __align__(16) unsigned short sm[SMSZ];
  __shared__ int sbatch[64];

  int tid = threadIdx.x;
  int l16 = tid & 15;
  int nl = tid >> 4;
  int row0 = blockIdx.x * 64;
  int node = row0 + nl;

  if (tid < 64) sbatch[tid] = (row0 + tid < N) ? batch[row0 + tid] : -1;

  // ---- phase 1 ----
  {
    const uint4* hp = (const uint4*)hin;
    float a0 = 0.f, a1 = 0.f, a2 = 0.f, a3 = 0.f, a4 = 0.f, a5 = 0.f, a6 = 0.f, a7 = 0.f;
    if (node < N) {
      uint4 u = hp[(size_t)node * 16 + l16];
      a0 = bflo(u.x); a1 = bfhi(u.x);
      a2 = bflo(u.y); a3 = bfhi(u.y);
      a4 = bflo(u.z); a5 = bfhi(u.z);
      a6 = bflo(u.w); a7 = bfhi(u.w);
      int e0 = rowptr[node], e1 = rowptr[node + 1];
      int e = e0;
      for (; e + 2 <= e1; e += 2) {
        int c0 = col[e], c1 = col[e + 1];
        uint4 v0 = hp[(size_t)c0 * 16 + l16];
        uint4 v1 = hp[(size_t)c1 * 16 + l16];
        a0 += bflo(v0.x); a1 += bfhi(v0.x);
        a2 += bflo(v0.y); a3 += bfhi(v0.y);
        a4 += bflo(v0.z); a5 += bfhi(v0.z);
        a6 += bflo(v0.w); a7 += bfhi(v0.w);
        a0 += bflo(v1.x); a1 += bfhi(v1.x);
        a2 += bflo(v1.y); a3 += bfhi(v1.y);
        a4 += bflo(v1.z); a5 += bfhi(v1.z);
        a6 += bflo(v1.w); a7 += bfhi(v1.w);
      }
      if (e < e1) {
        uint4 v0 = hp[(size_t)col[e] * 16 + l16];
        a0 += bflo(v0.x); a1 += bfhi(v0.x);
        a2 += bflo(v0.y); a3 += bfhi(v0.y);
        a4 += bflo(v0.z); a5 += bfhi(v0.z);
        a6 += bflo(v0.w); a7 += bfhi(v0.w);
      }
      float di = dinv[node];
      a0 *= di; a1 *= di; a2 *= di; a3 *= di;
      a4 *= di; a5 *= di; a6 *= di; a7 *= di;
    }
    uint4 o;
    o.x = (unsigned int)f2bf(a0) | ((unsigned int)f2bf(a1) << 16);
    o.y = (unsigned int)f2bf(a2) | ((unsigned int)f2bf(a3) << 16);
    o.z = (unsigned int)f2bf(a4) | ((unsigned int)f2bf(a5) << 16);
    o.w = (unsigned int)f2bf(a6) | ((unsigned int)f2bf(a7) << 16);
    *(uint4*)&sm[nl * KP + l16 * 8] = o;
  }
  __syncthreads();

  // ---- phase 2 (no epilogue scaling: pool needs raw h3) ----
  int wv = tid >> 6, lane = tid & 63, quad = lane >> 4, l15 = lane & 15;
  int rt = wv & 3, tp = wv >> 2;
  v8s af[KK];
#pragma unroll
  for (int kk = 0; kk < KK; ++kk)
    af[kk] = *(const v8s*)&sm[(rt * 16 + l15) * KP + kk * 32 + quad * 8];
  __syncthreads();

#pragma unroll
  for (int tt = 0; tt < 2; ++tt) {
    int t = tp * 2 + tt;
    v4f acc = {0.f, 0.f, 0.f, 0.f};
#pragma unroll
    for (int kk = 0; kk < KK; ++kk) {
      v8s bf = *(const v8s*)(WTF + (size_t)(((t * KK + kk) * 4 + quad) * 16 + l15) * 8);
      acc = __builtin_amdgcn_mfma_f32_16x16x32_bf16(af[kk], bf, acc, 0, 0, 0);
    }
    float bias = b[t * 16 + l15];
#pragma unroll
    for (int i = 0; i < 4; ++i) {
      float o = fmaxf(acc[i] + bias, 0.f);
      sm[(rt * 16 + quad * 4 + i) * CP + t * 16 + l15] = f2bf(o);
    }
  }
  __syncthreads();

  // ---- phase 3: segment-sum the 64 sorted rows, atomicAdd partials ----
  int f = tid & 127;
  int grp = tid >> 7;
  float run = 0.f;
  int cur = -1;
#pragma unroll
  for (int j = 0; j < 8; ++j) {
    int r = grp * 8 + j;
    int g = sbatch[r];
    if (g != cur) {
      if (cur >= 0) atomicAdd(&out[(size_t)cur * 128 + f], run);
      run = 0.f; cur = g;
    }
    if (g >= 0) run += bf2f(sm[r * CP + f]);
  }
  if (cur >= 0) atomicAdd(&out[(size_t)cur * 128 + f], run);
}

// divide pooled sums by segment counts
__global__ void k_finalize(float* __restrict__ out, const int* __restrict__ gstart, int G) {
  int idx = blockIdx.x * blockDim.x + threadIdx.x;
  if (idx >= G * 128) return;
  int g = idx >> 7;
  float cnt = (float)(gstart[g + 1] - gstart[g]);
  out[idx] = out[idx] / fmaxf(cnt, 1.f);
}

extern "C" void kernel_launch(void* const* d_in, const int* in_sizes, int n_in,
                              void* d_out, int out_size, void* d_ws, size_t ws_size,
                              hipStream_t stream) {
  const float* x  = (const float*)d_in[0];
  const int* ei   = (const int*)d_in[1];
  const int* batch = (const int*)d_in[2];
  const float* W1 = (const float*)d_in[3];
  const float* b1 = (const float*)d_in[4];
  const float* W2 = (const float*)d_in[5];
  const float* b2 = (const float*)d_in[6];
  const float* W3 = (const float*)d_in[7];
  const float* b3 = (const float*)d_in[8];
  float* out = (float*)d_out;
  int N = in_sizes[2];
  int E = in_sizes[1] / 2;
  int G = out_size / HD;
  const int* src = ei;
  const int* dst = ei + E;

  size_t off = 0;
  char* ws = (char*)d_ws;
  auto alloc = [&](size_t bytes) -> void* {
    void* p = ws + off;
    off += (bytes + 255) & ~(size_t)255;
    return p;
  };
  int nb1024 = (N + 1023) / 1024;
  int*   deg     = (int*)alloc((size_t)N * 4);        // N*4 is 256-aligned for N=200000
  int*   scanbuf = (int*)alloc((size_t)nb1024 * 4);   // contiguous after deg -> one memset
  float* dinv    = (float*)alloc((size_t)N * 4);
  int*   rowptr  = (int*)alloc((size_t)(N + 1) * 4);
  int*   eord    = (int*)alloc((size_t)E * 4);
  int*   col     = (int*)alloc((size_t)E * 4);
  int*   gstart  = (int*)alloc((size_t)(G + 1) * 4);
  unsigned short* xb  = (unsigned short*)alloc((size_t)N * 32 * 2);
  unsigned short* hA  = (unsigned short*)alloc((size_t)N * HD * 2);
  unsigned short* hB  = (unsigned short*)alloc((size_t)N * HD * 2);
  unsigned short* W1F = (unsigned short*)alloc(4096 * 2);
  unsigned short* W2F = (unsigned short*)alloc(16384 * 2);
  unsigned short* W3F = (unsigned short*)alloc(16384 * 2);
  (void)ws_size; (void)n_in;

  size_t zbytes = (size_t)((char*)dinv - (char*)deg);  // deg + scanbuf region
  hipMemsetAsync(deg, 0, zbytes, stream);
  k_degree<<<(E + 255) / 256, 256, 0, stream>>>(dst, deg, eord, E);
  k_scan<<<nb1024, 256, 0, stream>>>(deg, scanbuf, rowptr, dinv, N);

  int SB = (E + 255) / 256;
  int XB = (N * 32 + 255) / 256;
  int WB = 144;
  int BB = (N + 255) / 256;
  int ZB = (G * 32 + 255) / 256;   // out zero, float4/thread
  k_prep<<<SB + XB + WB + BB + ZB, 256, 0, stream>>>(src, dst, rowptr, eord, col, E,
                                                     x, dinv, xb, N,
                                                     W1, W2, W3, W1F, W2F, W3F,
                                                     batch, gstart, G, out,
                                                     SB, XB, WB, BB);

  int fusedBlocks = (N + 63) / 64;
  k_fused<32><<<fusedBlocks, 1024, 0, stream>>>(xb, W1F, b1, rowptr, col, dinv, hA, N);
  k_fused<128><<<fusedBlocks, 1024, 0, stream>>>(hA, W2F, b2, rowptr, col, dinv, hB, N);
  k_fused_pool<<<fusedBlocks, 1024, 0, stream>>>(hB, W3F, b3, rowptr, col, dinv, batch, out, N);
  k_finalize<<<(G * 128 + 255) / 256, 256, 0, stream>>>(out, gstart, G);
}